// Round 23
// baseline (1288.933 us; speedup 1.0000x reference)
//
#include <hip/hip_runtime.h>

// RGCNConv: out_i = x_i @ W_root + bias + sum_r mean_{j in N_r(i)} x_j @ W_r
//
// R23 = R22 with SORT-FREE aggregate: R22 showed ~16us per 256-edge block --
// the in-block counting sort (20 barriers, 128-bin scan) + serial per-seg
// gather chains were the cost, not traffic. New aggregate: accumulate edges
// DIRECTLY into a [128 seg][64 col] fp32 LDS tile via atomicAdd (epack already
// carries seg&127). Grid (NRUNS, 2): each block owns a 64-col half. 3 barriers,
// independent 4-deep gather ILP, ~2-way LDS atomic conflicts (stride 68).
// Sort pipeline / gemm unchanged (validated R21/R22).

constexpr int D = 128;
constexpr int R = 8;
constexpr int LDA = 40;
constexpr int TILE2 = 4096;
constexpr int CAP = 768;
constexpr int MAXRUNS = 8192;
constexpr int TCH = 32;

typedef __bf16 bf16x8 __attribute__((ext_vector_type(8)));
typedef float  f32x4  __attribute__((ext_vector_type(4)));
typedef unsigned short u16x8 __attribute__((ext_vector_type(8)));
typedef unsigned short u16x4 __attribute__((ext_vector_type(4)));

__device__ __forceinline__ unsigned short f2bf(float f) {
    unsigned u = __builtin_bit_cast(unsigned, f);
    u += 0x7FFFu + ((u >> 16) & 1u);
    return (unsigned short)(u >> 16);
}
__device__ __forceinline__ float bf2f(unsigned short h) {
    return __builtin_bit_cast(float, (unsigned)h << 16);
}

// ---- prep: role-split. [0,XB): x->bf16 | [XB,XB+NT): count | rest: wallt ----
constexpr int XB = 640;
constexpr int WB = 64;
__global__ __launch_bounds__(256)
void prep_kernel(const float* __restrict__ x, unsigned short* __restrict__ xbf,
                 int nquad,
                 const int* __restrict__ dst, const int* __restrict__ et,
                 unsigned short* __restrict__ counts, int E, int nruns, int ntiles,
                 const float* __restrict__ Wroot, const float* __restrict__ W,
                 unsigned short* __restrict__ WallTc) {
    __shared__ int lh[MAXRUNS];
    if (blockIdx.x < XB) {
        int stride = XB * 256;
        for (int i = blockIdx.x * 256 + threadIdx.x; i < nquad; i += stride) {
            float4 v = ((const float4*)x)[i];
            u16x4 o;
            o[0] = f2bf(v.x); o[1] = f2bf(v.y); o[2] = f2bf(v.z); o[3] = f2bf(v.w);
            ((u16x4*)xbf)[i] = o;
        }
    } else if (blockIdx.x < XB + (unsigned)ntiles) {
        int tile = blockIdx.x - XB;
        for (int i = threadIdx.x; i < nruns; i += 256) lh[i] = 0;
        __syncthreads();
        int t0 = tile * TILE2;
        #pragma unroll 4
        for (int j = 0; j < TILE2 / 256; ++j) {
            int e = t0 + j * 256 + threadIdx.x;
            if (e < E) {
                int seg = dst[e] * R + et[e];
                atomicAdd(&lh[seg >> 7], 1);
            }
        }
        __syncthreads();
        unsigned short* row = counts + (size_t)tile * nruns;
        for (int i = threadIdx.x; i < nruns; i += 256) row[i] = (unsigned short)lh[i];
    } else {
        int b = blockIdx.x - XB - ntiles;
        int stride = WB * 256;
        for (int idx = b * 256 + threadIdx.x; idx < 128 * 1152; idx += stride) {
            int n = idx / 1152, k = idx % 1152;
            float v = (k < 1024)
                ? W[(size_t)(k >> 7) * 16384 + (size_t)(k & 127) * 128 + n]
                : Wroot[(size_t)(k - 1024) * 128 + n];
            WallTc[idx] = f2bf(v);
        }
    }
}

// ---- hierarchical column scan (validated) ----
__global__ __launch_bounds__(256)
void colscanA_kernel(const unsigned short* __restrict__ counts, int* __restrict__ part,
                     int ntiles, int nruns, int cpt) {
    int r = blockIdx.x * 256 + threadIdx.x;
    int c = blockIdx.y;
    if (r >= nruns) return;
    int t0 = c * cpt, t1 = min(t0 + cpt, ntiles);
    int acc = 0;
    for (int t = t0; t < t1; ++t) acc += counts[(size_t)t * nruns + r];
    part[(size_t)c * nruns + r] = acc;
}

__global__ __launch_bounds__(256)
void colscanB_kernel(int* __restrict__ part, int* __restrict__ runtot,
                     int nchunks, int nruns) {
    int r = blockIdx.x * 256 + threadIdx.x;
    if (r >= nruns) return;
    int acc = 0;
    for (int c = 0; c < nchunks; ++c) {
        size_t i = (size_t)c * nruns + r;
        int v = part[i];
        part[i] = acc;
        acc += v;
    }
    runtot[r] = acc;
}

__global__ __launch_bounds__(256)
void colscanC_kernel(unsigned short* __restrict__ counts, const int* __restrict__ part,
                     int ntiles, int nruns, int cpt) {
    int r = blockIdx.x * 256 + threadIdx.x;
    int c = blockIdx.y;
    if (r >= nruns) return;
    int t0 = c * cpt, t1 = min(t0 + cpt, ntiles);
    int acc = part[(size_t)c * nruns + r];
    for (int t = t0; t < t1; ++t) {
        size_t i = (size_t)t * nruns + r;
        int v = counts[i];
        counts[i] = (unsigned short)acc;
        acc += v;
    }
}

__global__ __launch_bounds__(64)
void runscan_kernel(const int* __restrict__ runtot, int* __restrict__ runbase, int nb) {
    int lane = threadIdx.x;
    int carry = 0;
    for (int base = 0; base < nb; base += 64) {
        int i = base + lane;
        int orig = (i < nb) ? runtot[i] : 0;
        int v = orig;
        #pragma unroll
        for (int off = 1; off < 64; off <<= 1) {
            int u = __shfl_up(v, off, 64);
            if (lane >= off) v += u;
        }
        int tot = __shfl(v, 63, 64);
        if (i < nb) runbase[i] = carry + (v - orig);
        carry += tot;
    }
    if (lane == 0) runbase[nb] = carry;
}

// ---- place: exact positions, LDS-only atomics ----
__global__ __launch_bounds__(256)
void place_kernel(const int* __restrict__ src, const int* __restrict__ dst,
                  const int* __restrict__ et, const unsigned short* __restrict__ counts,
                  const int* __restrict__ runbase, unsigned* __restrict__ epack,
                  int E, int nruns) {
    __shared__ int lh[MAXRUNS];
    for (int i = threadIdx.x; i < nruns; i += 256) lh[i] = 0;
    __syncthreads();
    int t0 = blockIdx.x * TILE2;
    const unsigned short* colpre = counts + (size_t)blockIdx.x * nruns;
    #pragma unroll 4
    for (int j = 0; j < TILE2 / 256; ++j) {
        int e = t0 + j * 256 + threadIdx.x;
        if (e < E) {
            int seg  = dst[e] * R + et[e];
            int run  = seg >> 7;
            int rank = atomicAdd(&lh[run], 1);
            int pos  = runbase[run] + (int)colpre[run] + rank;
            epack[pos] = (unsigned)src[e] | ((unsigned)(seg & 127) << 24);
        }
    }
}

// ---- aggregate: sort-free LDS fp32 atomic tile. grid (NRUNS, 2) ----
__global__ __launch_bounds__(256)
void aggregate_kernel(const unsigned short* __restrict__ xbf,
                      const unsigned* __restrict__ epack,
                      const int* __restrict__ runbase,
                      unsigned short* __restrict__ mean,
                      int nseg) {
    __shared__ float    tile[128][68];   // 34.8 KB, stride 68 (~2-way atomic conflicts)
    __shared__ unsigned raw[CAP];
    __shared__ int      cntt[128];

    const int tid  = threadIdx.x;
    const int run  = blockIdx.x;
    const int c0   = blockIdx.y * 64;    // column half
    const int base = runbase[run];
    const int size = runbase[run + 1] - base;
    const int g    = tid >> 3;           // edge group 0..31 (8 threads/edge)
    const int c8   = tid & 7;            // col octet within the 64-col window

    // zero tile + cnt
    for (int i = tid; i < 128 * 68; i += 256) ((float*)tile)[i] = 0.0f;
    if (tid < 128) cntt[tid] = 0;
    __syncthreads();

    for (int off = 0; off < size; off += CAP) {
        int n = min(CAP, size - off);
        for (int j = tid; j < n; j += 256) raw[j] = epack[base + off + j];
        __syncthreads();

        // 4 independent edges in flight per thread
        for (int j = g; j < n; j += 128) {
            unsigned e0 = raw[j];
            bool ok1 = j + 32 < n, ok2 = j + 64 < n, ok3 = j + 96 < n;
            unsigned e1 = ok1 ? raw[j + 32] : 0;
            unsigned e2 = ok2 ? raw[j + 64] : 0;
            unsigned e3 = ok3 ? raw[j + 96] : 0;
            u16x8 v0 = *(const u16x8*)(xbf + ((size_t)(e0 & 0xFFFFFF) << 7) + c0 + c8 * 8);
            u16x8 v1, v2, v3;
            if (ok1) v1 = *(const u16x8*)(xbf + ((size_t)(e1 & 0xFFFFFF) << 7) + c0 + c8 * 8);
            if (ok2) v2 = *(const u16x8*)(xbf + ((size_t)(e2 & 0xFFFFFF) << 7) + c0 + c8 * 8);
            if (ok3) v3 = *(const u16x8*)(xbf + ((size_t)(e3 & 0xFFFFFF) << 7) + c0 + c8 * 8);

            int s0 = e0 >> 24;
            if (c8 == 0) atomicAdd(&cntt[s0], 1);
            #pragma unroll
            for (int q = 0; q < 8; ++q) atomicAdd(&tile[s0][c8 * 8 + q], bf2f(v0[q]));
            if (ok1) {
                int s = e1 >> 24;
                if (c8 == 0) atomicAdd(&cntt[s], 1);
                #pragma unroll
                for (int q = 0; q < 8; ++q) atomicAdd(&tile[s][c8 * 8 + q], bf2f(v1[q]));
            }
            if (ok2) {
                int s = e2 >> 24;
                if (c8 == 0) atomicAdd(&cntt[s], 1);
                #pragma unroll
                for (int q = 0; q < 8; ++q) atomicAdd(&tile[s][c8 * 8 + q], bf2f(v2[q]));
            }
            if (ok3) {
                int s = e3 >> 24;
                if (c8 == 0) atomicAdd(&cntt[s], 1);
                #pragma unroll
                for (int q = 0; q < 8; ++q) atomicAdd(&tile[s][c8 * 8 + q], bf2f(v3[q]));
            }
        }
        __syncthreads();   // raw reuse + atomics drained
    }

    // writeout: 2 threads per seg, 32 cols each. mean[node][1024] WallTc k-order.
    const int s  = tid >> 1;
    const int hf = tid & 1;
    const int seg = run * 128 + s;
    if (seg < nseg) {
        int cn = cntt[s];
        float inv = (cn > 0) ? 1.0f / (float)cn : 0.0f;
        int node = seg >> 3, r = seg & 7;
        unsigned short* mp = mean + ((size_t)node << 10) + r * 128 + c0 + hf * 32;
        #pragma unroll
        for (int b = 0; b < 4; ++b) {
            u16x8 o;
            #pragma unroll
            for (int q = 0; q < 8; ++q)
                o[q] = f2bf(tile[s][hf * 32 + b * 8 + q] * inv);
            *(u16x8*)(mp + b * 8) = o;
        }
    }
}

// ---- GEMM: 3-stage LDS ring, loads issued 2 tiles ahead (validated R21) ----
__global__ __launch_bounds__(256)
void mfma_gemm_kernel(const unsigned short* __restrict__ xbf,
                      const unsigned short* __restrict__ mean,   // [node][1024]
                      const unsigned short* __restrict__ WallTc,
                      const float* __restrict__ bias,
                      float* __restrict__ out, int N) {
    constexpr int NT = 36;
    constexpr int ABUF = 64 * LDA;
    constexpr int BBUF = 128 * LDA;
    __shared__ unsigned short As[3][ABUF];
    __shared__ unsigned short Bs[3][BBUF];
    const int tid  = threadIdx.x;
    const int nd0  = blockIdx.x * 64;
    const int lane = tid & 63;
    const int wid  = tid >> 6;
    const int wm   = wid >> 1;
    const int wn   = wid & 1;
    const int arow = tid >> 2;
    const int aoct = tid & 3;
    const int brow = tid >> 1;
    const int bhalf = tid & 1;

    f32x4 acc[2][4] = {};

    const int  anode = nd0 + arow;
    const bool aok   = anode < N;

    auto loadG = [&](int kt, u16x8& av8, u16x8& b0, u16x8& b1) {
        #pragma unroll
        for (int j = 0; j < 8; ++j) av8[j] = 0;
        int kbase;
        if (kt < 4) {
            if (aok)
                av8 = *(const u16x8*)(xbf + ((size_t)anode << 7) + kt * 32 + aoct * 8);
            kbase = 1024 + kt * 32;
        } else {
            int lk = (kt - 4) * 32;
            if (aok)
                av8 = *(const u16x8*)(mean + ((size_t)anode << 10) + lk + aoct * 8);
            kbase = lk;
        }
        const u16x8* wp = (const u16x8*)(WallTc + (size_t)brow * 1152 + kbase + bhalf * 16);
        b0 = wp[0];
        b1 = wp[1];
    };
    auto storeT = [&](int buf, const u16x8& av8, const u16x8& b0, const u16x8& b1) {
        *(u16x8*)&As[buf][arow * LDA + aoct * 8]       = av8;
        *(u16x8*)&Bs[buf][brow * LDA + bhalf * 16]     = b0;
        *(u16x8*)&Bs[buf][brow * LDA + bhalf * 16 + 8] = b1;
    };

    const int ko = (lane >> 4) * 8;
    const int rl = lane & 15;
    auto compute = [&](int buf) {
        bf16x8 af[2], bf[4];
        #pragma unroll
        for (int f = 0; f < 2; ++f)
            af[f] = __builtin_bit_cast(bf16x8,
                *(const u16x8*)&As[buf][(wm * 32 + f * 16 + rl) * LDA + ko]);
        #pragma unroll
        for (int f = 0; f < 4; ++f)
            bf[f] = __builtin_bit_cast(bf16x8,
                *(const u16x8*)&Bs[buf][(wn * 64 + f * 16 + rl) * LDA + ko]);
        #pragma unroll
        for (int mf = 0; mf < 2; ++mf)
            #pragma unroll
            for (int nf = 0; nf < 4; ++nf)
                acc[mf][nf] = __builtin_amdgcn_mfma_f32_16x16x32_bf16(af[mf], bf[nf],
                                                                     acc[mf][nf], 0, 0, 0);
    };

    u16x8 aA, bA0, bA1, aB, bB0, bB1;
    loadG(0, aA, bA0, bA1);
    storeT(0, aA, bA0, bA1);
    loadG(1, aA, bA0, bA1);
    __syncthreads();

    int cb = 0;
    for (int kt = 0; kt < NT; kt += 2) {
        if (kt + 2 < NT) loadG(kt + 2, aB, bB0, bB1);
        compute(cb);
        if (kt + 1 < NT) storeT((cb + 1) % 3, aA, bA0, bA1);
        __syncthreads();
        cb = (cb + 1) % 3;
        if (kt + 1 < NT) {
            if (kt + 3 < NT) loadG(kt + 3, aA, bA0, bA1);
            compute(cb);
            if (kt + 2 < NT) storeT((cb + 1) % 3, aB, bB0, bB1);
            __syncthreads();
            cb = (cb + 1) % 3;
        }
    }

    const int rg = lane >> 4;
    #pragma unroll
    for (int nf = 0; nf < 4; ++nf) {
        int n = wn * 64 + nf * 16 + rl;
        float bb = bias[n];
        #pragma unroll
        for (int mf = 0; mf < 2; ++mf) {
            #pragma unroll
            for (int i = 0; i < 4; ++i) {
                int nd = nd0 + wm * 32 + mf * 16 + rg * 4 + i;
                if (nd < N) out[(size_t)nd * 128 + n] = acc[mf][nf][i] + bb;
            }
        }
    }
}

extern "C" void kernel_launch(void* const* d_in, const int* in_sizes, int n_in,
                              void* d_out, int out_size, void* d_ws, size_t ws_size,
                              hipStream_t stream) {
    const float* x     = (const float*)d_in[0];
    const float* W     = (const float*)d_in[1];
    const float* Wroot = (const float*)d_in[2];
    const float* bias  = (const float*)d_in[3];
    const int*   ei    = (const int*)d_in[4];
    const int*   et    = (const int*)d_in[5];
    float*       out   = (float*)d_out;

    const int N = in_sizes[0] / D;
    const int E = in_sizes[5];
    const int* src = ei;
    const int* dst = ei + E;

    const int NSEG   = N * R;
    const int NRUNS  = (NSEG + 127) / 128;
    const int NTILES = (E + TILE2 - 1) / TILE2;
    if (NRUNS > MAXRUNS) return;

    const size_t mean_bytes   = (size_t)N * 1024 * 2;
    const size_t xbf_bytes    = (size_t)N * D * 2;
    const size_t walltc_bytes = (size_t)128 * 1152 * 2;
    const size_t counts_bytes = (size_t)NTILES * NRUNS * 2;
    const size_t part_bytes   = (size_t)TCH * NRUNS * 4;
    const size_t need = mean_bytes + xbf_bytes + walltc_bytes + counts_bytes +
                        part_bytes + ((size_t)NRUNS + (NRUNS + 1) + E) * 4 + 512;
    if (ws_size < need) return;

    char* p = (char*)d_ws;
    unsigned short* mean   = (unsigned short*)p;  p += mean_bytes;
    unsigned short* xbf    = (unsigned short*)p;  p += xbf_bytes;
    unsigned short* WallTc = (unsigned short*)p;  p += walltc_bytes;
    unsigned short* counts = (unsigned short*)p;  p += counts_bytes;
    int*      part    = (int*)p;       p += part_bytes;
    int*      runtot  = (int*)p;       p += (size_t)NRUNS * 4;
    int*      runbase = (int*)p;       p += (size_t)(NRUNS + 1) * 4;
    unsigned* epack   = (unsigned*)p;

    prep_kernel<<<XB + NTILES + WB, 256, 0, stream>>>(
        x, xbf, N * D / 4, dst, et, counts, E, NRUNS, NTILES, Wroot, W, WallTc);

    const int cpt = (NTILES + TCH - 1) / TCH;
    dim3 cgrid((NRUNS + 255) / 256, TCH);
    colscanA_kernel<<<cgrid, 256, 0, stream>>>(counts, part, NTILES, NRUNS, cpt);
    colscanB_kernel<<<(NRUNS + 255) / 256, 256, 0, stream>>>(part, runtot, TCH, NRUNS);
    colscanC_kernel<<<cgrid, 256, 0, stream>>>(counts, part, NTILES, NRUNS, cpt);
    runscan_kernel<<<1, 64, 0, stream>>>(runtot, runbase, NRUNS);

    place_kernel<<<NTILES, 256, 0, stream>>>(src, dst, et, counts, runbase, epack, E, NRUNS);

    aggregate_kernel<<<dim3(NRUNS, 2), 256, 0, stream>>>(xbf, epack, runbase, mean, NSEG);

    const int gx = (N + 63) / 64;
    mfma_gemm_kernel<<<gx, 256, 0, stream>>>(xbf, mean, WallTc, bias, out, N);
}

// Round 24
// 350.678 us; speedup vs baseline: 3.6755x; 3.6755x over previous
//
#include <hip/hip_runtime.h>

// RGCNConv: out_i = x_i @ W_root + bias + sum_r mean_{j in N_r(i)} x_j @ W_r
//
// R24 = exact revert to R22 (session best, 349.6 us) after R23's LDS-atomic
// aggregate regressed 8.5x (LDS fp32 atomicAdd serializes; never again).
// Pipeline: prep(xbf|count|wallt role-split) -> hierarchical colscan ->
// runscan -> place (exact positions, LDS-only int atomics) ->
// aggregate (in-LDS counting sort, reg accum, CAP=768) ->
// gemm (BM=64 MFMA, 3-stage LDS ring, loads 2 tiles ahead).

constexpr int D = 128;
constexpr int R = 8;
constexpr int LDA = 40;
constexpr int TILE2 = 4096;
constexpr int CAP = 768;
constexpr int MAXRUNS = 8192;
constexpr int TCH = 32;

typedef __bf16 bf16x8 __attribute__((ext_vector_type(8)));
typedef float  f32x4  __attribute__((ext_vector_type(4)));
typedef unsigned short u16x8 __attribute__((ext_vector_type(8)));
typedef unsigned short u16x4 __attribute__((ext_vector_type(4)));

__device__ __forceinline__ unsigned short f2bf(float f) {
    unsigned u = __builtin_bit_cast(unsigned, f);
    u += 0x7FFFu + ((u >> 16) & 1u);
    return (unsigned short)(u >> 16);
}
__device__ __forceinline__ float bf2f(unsigned short h) {
    return __builtin_bit_cast(float, (unsigned)h << 16);
}

// ---- prep: role-split. [0,XB): x->bf16 | [XB,XB+NT): count | rest: wallt ----
constexpr int XB = 640;
constexpr int WB = 64;
__global__ __launch_bounds__(256)
void prep_kernel(const float* __restrict__ x, unsigned short* __restrict__ xbf,
                 int nquad,
                 const int* __restrict__ dst, const int* __restrict__ et,
                 unsigned short* __restrict__ counts, int E, int nruns, int ntiles,
                 const float* __restrict__ Wroot, const float* __restrict__ W,
                 unsigned short* __restrict__ WallTc) {
    __shared__ int lh[MAXRUNS];
    if (blockIdx.x < XB) {
        int stride = XB * 256;
        for (int i = blockIdx.x * 256 + threadIdx.x; i < nquad; i += stride) {
            float4 v = ((const float4*)x)[i];
            u16x4 o;
            o[0] = f2bf(v.x); o[1] = f2bf(v.y); o[2] = f2bf(v.z); o[3] = f2bf(v.w);
            ((u16x4*)xbf)[i] = o;
        }
    } else if (blockIdx.x < XB + (unsigned)ntiles) {
        int tile = blockIdx.x - XB;
        for (int i = threadIdx.x; i < nruns; i += 256) lh[i] = 0;
        __syncthreads();
        int t0 = tile * TILE2;
        #pragma unroll 4
        for (int j = 0; j < TILE2 / 256; ++j) {
            int e = t0 + j * 256 + threadIdx.x;
            if (e < E) {
                int seg = dst[e] * R + et[e];
                atomicAdd(&lh[seg >> 7], 1);
            }
        }
        __syncthreads();
        unsigned short* row = counts + (size_t)tile * nruns;
        for (int i = threadIdx.x; i < nruns; i += 256) row[i] = (unsigned short)lh[i];
    } else {
        int b = blockIdx.x - XB - ntiles;
        int stride = WB * 256;
        for (int idx = b * 256 + threadIdx.x; idx < 128 * 1152; idx += stride) {
            int n = idx / 1152, k = idx % 1152;
            float v = (k < 1024)
                ? W[(size_t)(k >> 7) * 16384 + (size_t)(k & 127) * 128 + n]
                : Wroot[(size_t)(k - 1024) * 128 + n];
            WallTc[idx] = f2bf(v);
        }
    }
}

// ---- hierarchical column scan (validated) ----
__global__ __launch_bounds__(256)
void colscanA_kernel(const unsigned short* __restrict__ counts, int* __restrict__ part,
                     int ntiles, int nruns, int cpt) {
    int r = blockIdx.x * 256 + threadIdx.x;
    int c = blockIdx.y;
    if (r >= nruns) return;
    int t0 = c * cpt, t1 = min(t0 + cpt, ntiles);
    int acc = 0;
    for (int t = t0; t < t1; ++t) acc += counts[(size_t)t * nruns + r];
    part[(size_t)c * nruns + r] = acc;
}

__global__ __launch_bounds__(256)
void colscanB_kernel(int* __restrict__ part, int* __restrict__ runtot,
                     int nchunks, int nruns) {
    int r = blockIdx.x * 256 + threadIdx.x;
    if (r >= nruns) return;
    int acc = 0;
    for (int c = 0; c < nchunks; ++c) {
        size_t i = (size_t)c * nruns + r;
        int v = part[i];
        part[i] = acc;
        acc += v;
    }
    runtot[r] = acc;
}

__global__ __launch_bounds__(256)
void colscanC_kernel(unsigned short* __restrict__ counts, const int* __restrict__ part,
                     int ntiles, int nruns, int cpt) {
    int r = blockIdx.x * 256 + threadIdx.x;
    int c = blockIdx.y;
    if (r >= nruns) return;
    int t0 = c * cpt, t1 = min(t0 + cpt, ntiles);
    int acc = part[(size_t)c * nruns + r];
    for (int t = t0; t < t1; ++t) {
        size_t i = (size_t)t * nruns + r;
        int v = counts[i];
        counts[i] = (unsigned short)acc;
        acc += v;
    }
}

__global__ __launch_bounds__(64)
void runscan_kernel(const int* __restrict__ runtot, int* __restrict__ runbase, int nb) {
    int lane = threadIdx.x;
    int carry = 0;
    for (int base = 0; base < nb; base += 64) {
        int i = base + lane;
        int orig = (i < nb) ? runtot[i] : 0;
        int v = orig;
        #pragma unroll
        for (int off = 1; off < 64; off <<= 1) {
            int u = __shfl_up(v, off, 64);
            if (lane >= off) v += u;
        }
        int tot = __shfl(v, 63, 64);
        if (i < nb) runbase[i] = carry + (v - orig);
        carry += tot;
    }
    if (lane == 0) runbase[nb] = carry;
}

// ---- place: exact positions, LDS-only atomics ----
__global__ __launch_bounds__(256)
void place_kernel(const int* __restrict__ src, const int* __restrict__ dst,
                  const int* __restrict__ et, const unsigned short* __restrict__ counts,
                  const int* __restrict__ runbase, unsigned* __restrict__ epack,
                  int E, int nruns) {
    __shared__ int lh[MAXRUNS];
    for (int i = threadIdx.x; i < nruns; i += 256) lh[i] = 0;
    __syncthreads();
    int t0 = blockIdx.x * TILE2;
    const unsigned short* colpre = counts + (size_t)blockIdx.x * nruns;
    #pragma unroll 4
    for (int j = 0; j < TILE2 / 256; ++j) {
        int e = t0 + j * 256 + threadIdx.x;
        if (e < E) {
            int seg  = dst[e] * R + et[e];
            int run  = seg >> 7;
            int rank = atomicAdd(&lh[run], 1);
            int pos  = runbase[run] + (int)colpre[run] + rank;
            epack[pos] = (unsigned)src[e] | ((unsigned)(seg & 127) << 24);
        }
    }
}

// ---- aggregate: single pass, NOCT=16, CAP=768. mean[node][1024] ----
__global__ __launch_bounds__(256)
void aggregate_kernel(const unsigned short* __restrict__ xbf,
                      const unsigned* __restrict__ epack,
                      const int* __restrict__ runbase,
                      unsigned short* __restrict__ mean,
                      int nseg) {
    __shared__ unsigned raw[CAP];
    __shared__ unsigned srt[CAP];
    __shared__ int hist[128], sc[128], offs[128], cur[128];

    const int tid  = threadIdx.x;
    const int run  = blockIdx.x;
    const int base = runbase[run];
    const int size = runbase[run + 1] - base;
    const int c8   = tid & 15;
    const int sg0  = tid >> 4;

    float a[8][8] = {};
    int   cacc[8] = {};

    const int nchunks = (size + CAP - 1) / CAP;
    for (int ch = 0; ch < nchunks; ++ch) {
        int off = ch * CAP;
        int n   = min(CAP, size - off);

        if (tid < 128) hist[tid] = 0;
        __syncthreads();
        for (int j = tid; j < n; j += 256) {
            unsigned e = epack[base + off + j];
            raw[j] = e;
            atomicAdd(&hist[e >> 24], 1);
        }
        __syncthreads();
        if (tid < 128) sc[tid] = hist[tid];
        __syncthreads();
        for (int o = 1; o < 128; o <<= 1) {
            int u = 0;
            if (tid < 128 && tid >= o) u = sc[tid - o];
            __syncthreads();
            if (tid < 128) sc[tid] += u;
            __syncthreads();
        }
        if (tid < 128) { int x0 = sc[tid] - hist[tid]; offs[tid] = x0; cur[tid] = x0; }
        __syncthreads();
        for (int j = tid; j < n; j += 256) {
            unsigned e = raw[j];
            int r = atomicAdd(&cur[e >> 24], 1);
            srt[r] = e;
        }
        __syncthreads();
        #pragma unroll
        for (int i = 0; i < 8; ++i) {
            int s  = sg0 + i * 16;
            int st = offs[s], cn = hist[s];
            cacc[i] += cn;
            for (int k = 0; k < cn; k += 4) {
                unsigned e0 = srt[st + k];
                int s1ok = (k + 1 < cn), s2ok = (k + 2 < cn), s3ok = (k + 3 < cn);
                unsigned e1 = s1ok ? srt[st + k + 1] : 0;
                unsigned e2 = s2ok ? srt[st + k + 2] : 0;
                unsigned e3 = s3ok ? srt[st + k + 3] : 0;
                u16x8 v0 = *(const u16x8*)(xbf + ((size_t)(e0 & 0xFFFFFF) << 7) + c8 * 8);
                #pragma unroll
                for (int q = 0; q < 8; ++q) a[i][q] += bf2f(v0[q]);
                if (s1ok) {
                    u16x8 v = *(const u16x8*)(xbf + ((size_t)(e1 & 0xFFFFFF) << 7) + c8 * 8);
                    #pragma unroll
                    for (int q = 0; q < 8; ++q) a[i][q] += bf2f(v[q]);
                }
                if (s2ok) {
                    u16x8 v = *(const u16x8*)(xbf + ((size_t)(e2 & 0xFFFFFF) << 7) + c8 * 8);
                    #pragma unroll
                    for (int q = 0; q < 8; ++q) a[i][q] += bf2f(v[q]);
                }
                if (s3ok) {
                    u16x8 v = *(const u16x8*)(xbf + ((size_t)(e3 & 0xFFFFFF) << 7) + c8 * 8);
                    #pragma unroll
                    for (int q = 0; q < 8; ++q) a[i][q] += bf2f(v[q]);
                }
            }
        }
        __syncthreads();
    }

    // mean[node][1024] in WallTc k-order: idx = node*1024 + r*128 + col
    #pragma unroll
    for (int i = 0; i < 8; ++i) {
        int seg = run * 128 + sg0 + i * 16;       // seg = node*8 + r
        if (seg < nseg) {
            int node = seg >> 3, r = seg & 7;
            float inv = (cacc[i] > 0) ? 1.0f / (float)cacc[i] : 0.0f;
            u16x8 o;
            #pragma unroll
            for (int q = 0; q < 8; ++q) o[q] = f2bf(a[i][q] * inv);
            *(u16x8*)(mean + ((size_t)node << 10) + r * 128 + c8 * 8) = o;
        }
    }
}

// ---- GEMM: 3-stage LDS ring, loads issued 2 tiles ahead (validated R21) ----
__global__ __launch_bounds__(256)
void mfma_gemm_kernel(const unsigned short* __restrict__ xbf,
                      const unsigned short* __restrict__ mean,   // [node][1024]
                      const unsigned short* __restrict__ WallTc,
                      const float* __restrict__ bias,
                      float* __restrict__ out, int N) {
    constexpr int NT = 36;
    constexpr int ABUF = 64 * LDA;
    constexpr int BBUF = 128 * LDA;
    __shared__ unsigned short As[3][ABUF];
    __shared__ unsigned short Bs[3][BBUF];
    const int tid  = threadIdx.x;
    const int nd0  = blockIdx.x * 64;
    const int lane = tid & 63;
    const int wid  = tid >> 6;
    const int wm   = wid >> 1;
    const int wn   = wid & 1;
    const int arow = tid >> 2;
    const int aoct = tid & 3;
    const int brow = tid >> 1;
    const int bhalf = tid & 1;

    f32x4 acc[2][4] = {};

    const int  anode = nd0 + arow;
    const bool aok   = anode < N;

    auto loadG = [&](int kt, u16x8& av8, u16x8& b0, u16x8& b1) {
        #pragma unroll
        for (int j = 0; j < 8; ++j) av8[j] = 0;
        int kbase;
        if (kt < 4) {
            if (aok)
                av8 = *(const u16x8*)(xbf + ((size_t)anode << 7) + kt * 32 + aoct * 8);
            kbase = 1024 + kt * 32;
        } else {
            int lk = (kt - 4) * 32;
            if (aok)
                av8 = *(const u16x8*)(mean + ((size_t)anode << 10) + lk + aoct * 8);
            kbase = lk;
        }
        const u16x8* wp = (const u16x8*)(WallTc + (size_t)brow * 1152 + kbase + bhalf * 16);
        b0 = wp[0];
        b1 = wp[1];
    };
    auto storeT = [&](int buf, const u16x8& av8, const u16x8& b0, const u16x8& b1) {
        *(u16x8*)&As[buf][arow * LDA + aoct * 8]       = av8;
        *(u16x8*)&Bs[buf][brow * LDA + bhalf * 16]     = b0;
        *(u16x8*)&Bs[buf][brow * LDA + bhalf * 16 + 8] = b1;
    };

    const int ko = (lane >> 4) * 8;
    const int rl = lane & 15;
    auto compute = [&](int buf) {
        bf16x8 af[2], bf[4];
        #pragma unroll
        for (int f = 0; f < 2; ++f)
            af[f] = __builtin_bit_cast(bf16x8,
                *(const u16x8*)&As[buf][(wm * 32 + f * 16 + rl) * LDA + ko]);
        #pragma unroll
        for (int f = 0; f < 4; ++f)
            bf[f] = __builtin_bit_cast(bf16x8,
                *(const u16x8*)&Bs[buf][(wn * 64 + f * 16 + rl) * LDA + ko]);
        #pragma unroll
        for (int mf = 0; mf < 2; ++mf)
            #pragma unroll
            for (int nf = 0; nf < 4; ++nf)
                acc[mf][nf] = __builtin_amdgcn_mfma_f32_16x16x32_bf16(af[mf], bf[nf],
                                                                     acc[mf][nf], 0, 0, 0);
    };

    u16x8 aA, bA0, bA1, aB, bB0, bB1;
    loadG(0, aA, bA0, bA1);
    storeT(0, aA, bA0, bA1);
    loadG(1, aA, bA0, bA1);
    __syncthreads();

    int cb = 0;
    for (int kt = 0; kt < NT; kt += 2) {
        if (kt + 2 < NT) loadG(kt + 2, aB, bB0, bB1);
        compute(cb);
        if (kt + 1 < NT) storeT((cb + 1) % 3, aA, bA0, bA1);
        __syncthreads();
        cb = (cb + 1) % 3;
        if (kt + 1 < NT) {
            if (kt + 3 < NT) loadG(kt + 3, aA, bA0, bA1);
            compute(cb);
            if (kt + 2 < NT) storeT((cb + 1) % 3, aB, bB0, bB1);
            __syncthreads();
            cb = (cb + 1) % 3;
        }
    }

    const int rg = lane >> 4;
    #pragma unroll
    for (int nf = 0; nf < 4; ++nf) {
        int n = wn * 64 + nf * 16 + rl;
        float bb = bias[n];
        #pragma unroll
        for (int mf = 0; mf < 2; ++mf) {
            #pragma unroll
            for (int i = 0; i < 4; ++i) {
                int nd = nd0 + wm * 32 + mf * 16 + rg * 4 + i;
                if (nd < N) out[(size_t)nd * 128 + n] = acc[mf][nf][i] + bb;
            }
        }
    }
}

extern "C" void kernel_launch(void* const* d_in, const int* in_sizes, int n_in,
                              void* d_out, int out_size, void* d_ws, size_t ws_size,
                              hipStream_t stream) {
    const float* x     = (const float*)d_in[0];
    const float* W     = (const float*)d_in[1];
    const float* Wroot = (const float*)d_in[2];
    const float* bias  = (const float*)d_in[3];
    const int*   ei    = (const int*)d_in[4];
    const int*   et    = (const int*)d_in[5];
    float*       out   = (float*)d_out;

    const int N = in_sizes[0] / D;
    const int E = in_sizes[5];
    const int* src = ei;
    const int* dst = ei + E;

    const int NSEG   = N * R;
    const int NRUNS  = (NSEG + 127) / 128;
    const int NTILES = (E + TILE2 - 1) / TILE2;
    if (NRUNS > MAXRUNS) return;

    const size_t mean_bytes   = (size_t)N * 1024 * 2;
    const size_t xbf_bytes    = (size_t)N * D * 2;
    const size_t walltc_bytes = (size_t)128 * 1152 * 2;
    const size_t counts_bytes = (size_t)NTILES * NRUNS * 2;
    const size_t part_bytes   = (size_t)TCH * NRUNS * 4;
    const size_t need = mean_bytes + xbf_bytes + walltc_bytes + counts_bytes +
                        part_bytes + ((size_t)NRUNS + (NRUNS + 1) + E) * 4 + 512;
    if (ws_size < need) return;

    char* p = (char*)d_ws;
    unsigned short* mean   = (unsigned short*)p;  p += mean_bytes;
    unsigned short* xbf    = (unsigned short*)p;  p += xbf_bytes;
    unsigned short* WallTc = (unsigned short*)p;  p += walltc_bytes;
    unsigned short* counts = (unsigned short*)p;  p += counts_bytes;
    int*      part    = (int*)p;       p += part_bytes;
    int*      runtot  = (int*)p;       p += (size_t)NRUNS * 4;
    int*      runbase = (int*)p;       p += (size_t)(NRUNS + 1) * 4;
    unsigned* epack   = (unsigned*)p;

    prep_kernel<<<XB + NTILES + WB, 256, 0, stream>>>(
        x, xbf, N * D / 4, dst, et, counts, E, NRUNS, NTILES, Wroot, W, WallTc);

    const int cpt = (NTILES + TCH - 1) / TCH;
    dim3 cgrid((NRUNS + 255) / 256, TCH);
    colscanA_kernel<<<cgrid, 256, 0, stream>>>(counts, part, NTILES, NRUNS, cpt);
    colscanB_kernel<<<(NRUNS + 255) / 256, 256, 0, stream>>>(part, runtot, TCH, NRUNS);
    colscanC_kernel<<<cgrid, 256, 0, stream>>>(counts, part, NTILES, NRUNS, cpt);
    runscan_kernel<<<1, 64, 0, stream>>>(runtot, runbase, NRUNS);

    place_kernel<<<NTILES, 256, 0, stream>>>(src, dst, et, counts, runbase, epack, E, NRUNS);

    aggregate_kernel<<<NRUNS, 256, 0, stream>>>(xbf, epack, runbase, mean, NSEG);

    const int gx = (N + 63) / 64;
    mfma_gemm_kernel<<<gx, 256, 0, stream>>>(xbf, mean, WallTc, bias, out, N);
}